// Round 9
// baseline (730.335 us; speedup 1.0000x reference)
//
#include <hip/hip_runtime.h>
#include <hip/hip_bf16.h>

// GAE: 8 stacked GAT layers on N=4096 nodes, dims 512->256->128->64->16->64->128->256->512.
// Outputs (concat in d_out): x_bar[4096*512], h1[4096*256], h2[4096*128], h3[4096*64], h4[4096*16].
//
// Per layer:
//   H = X @ W                      (bf16 MFMA GEMM, fp32 accum; HTt bf16 j-tiled layout written
//                                   directly from the GEMM epilogue via LDS)
//   src = H @ a[:f], tgt = H @ a[f:]; Ev=exp(t-TM), Gv=exp(0.2(t-TM)) with CONSTANT TM=12
//     (factorization exact for any upper bound TM >= max tgt)
//   pass1b: lsum_i = sum_{j in N(i)} max(P_i*Ev_j, Q_i*Gv_j); Av=P/lsum, Bv=Q/lsum (no exp in loop)
//   pass2p: OUT[i,:] = sum_j max(Av_i*Ev_j, Bv_i*Gv_j) * H[j,:]  == softmax(lrelu masked) @ H
// pass2p: 4 waves/block, each wave owns 16 rows completely; SOFTWARE-PIPELINED j-loop with
// ping-pong register buffers (loads for iter k+1 issued before compute of iter k) -> L2 latency
// hidden behind compute, no barriers/LDS/atomics -> bitwise deterministic. js>1 layers write
// per-z partials (aliased to dead H buffer) + deterministic reduce. HTt[j/32][f][j%32] keeps
// B loads contiguous. adj packed to a 2MB bitmask once, reused by all 8 layers.

#define NROWS 4096
#define TMC 12.0f

typedef __attribute__((ext_vector_type(8))) short v8s;
typedef __attribute__((ext_vector_type(4))) float v4f;

__device__ inline unsigned short f2bf(float x) {
  union { float f; unsigned u; } v; v.f = x;
  unsigned r = v.u + 0x7fffu + ((v.u >> 16) & 1u);   // RNE
  return (unsigned short)(r >> 16);
}

// ---- pack adj (int32 0/1) -> bitmask, 64 uint64 words per row ----
__global__ void pack_adj(const int* __restrict__ adj, unsigned long long* __restrict__ bits) {
  int row = blockIdx.x;
  int lane = threadIdx.x & 63, wave = threadIdx.x >> 6;
  for (int w = wave; w < 64; w += 4) {
    unsigned long long m = __ballot(adj[(size_t)row * NROWS + w * 64 + lane] > 0);
    if (lane == 0) bits[row * 64 + w] = m;
  }
}

// ---- batched W transpose: fp32 [K][F] -> bf16 [F][K], all 8 layers in one launch ----
struct WTArgs { const float* src[8]; unsigned short* dst[8]; int K[8]; int F[8]; };
__global__ void transpose_w(WTArgs A) {
  int z = blockIdx.z;
  const float* in = A.src[z];
  unsigned short* out = A.dst[z];
  int R = A.K[z], C = A.F[z];
  __shared__ unsigned short tile[32][33];
  int c0 = blockIdx.x * 32, r0 = blockIdx.y * 32;
  if (c0 >= C || r0 >= R) return;          // block-uniform: safe before barrier
#pragma unroll
  for (int dy = 0; dy < 32; dy += 8) {
    int r = r0 + threadIdx.y + dy, c = c0 + threadIdx.x;
    if (r < R && c < C) tile[threadIdx.y + dy][threadIdx.x] = f2bf(in[(size_t)r * C + c]);
  }
  __syncthreads();
#pragma unroll
  for (int dy = 0; dy < 32; dy += 8) {
    int c = c0 + threadIdx.y + dy, r = r0 + threadIdx.x;
    if (r < R && c < C) out[(size_t)c * R + r] = tile[threadIdx.x][threadIdx.y + dy];
  }
}

// ---- C[4096][Nf] = A_f32[4096][K] x B[K][Nf], B given as BT[Nf][K] bf16 ----
// 2 waves/block, 16 rows each; grid (128, ceil(Nf/64)).
// Epilogue also writes HTt[j/32][f][j%32] bf16 directly (LDS-staged) -> no separate transpose.
__global__ __launch_bounds__(128) void gemm_xw(const float* __restrict__ A,
                                               const unsigned short* __restrict__ BT,
                                               float* __restrict__ C,
                                               unsigned short* __restrict__ HTt,
                                               int K, int Nf) {
  __shared__ unsigned short zone[64 * 36];         // [f_local][j_local], stride 36 vs banks
  int lane = threadIdx.x & 63, wave = threadIdx.x >> 6;
  int quad = lane >> 4, l16 = lane & 15;
  int row0 = blockIdx.x * 32 + wave * 16;
  int col0 = blockIdx.y * 64;
  int nf = Nf - col0; nf = nf > 64 ? 4 : (nf + 15) / 16;
  v4f acc[4] = {{0.f,0.f,0.f,0.f},{0.f,0.f,0.f,0.f},{0.f,0.f,0.f,0.f},{0.f,0.f,0.f,0.f}};
  for (int k0 = 0; k0 < K; k0 += 32) {
    int kk = k0 + quad * 8;
    v8s a = {0,0,0,0,0,0,0,0};
    if (kk < K) {
      float4 f0 = *(const float4*)(A + (size_t)(row0 + l16) * K + kk);
      float4 f1 = *(const float4*)(A + (size_t)(row0 + l16) * K + kk + 4);
      union { v8s s; __hip_bfloat162 h[4]; } ua;
      ua.h[0] = __float22bfloat162_rn(make_float2(f0.x, f0.y));
      ua.h[1] = __float22bfloat162_rn(make_float2(f0.z, f0.w));
      ua.h[2] = __float22bfloat162_rn(make_float2(f1.x, f1.y));
      ua.h[3] = __float22bfloat162_rn(make_float2(f1.z, f1.w));
      a = ua.s;
    }
    for (int t = 0; t < nf; t++) {
      v8s b = {0,0,0,0,0,0,0,0};
      if (kk < K) b = *(const v8s*)(BT + (size_t)(col0 + t * 16 + l16) * K + kk);
      acc[t] = __builtin_amdgcn_mfma_f32_16x16x32_bf16(a, b, acc[t], 0, 0, 0);
    }
  }
  for (int t = 0; t < nf; t++) {
#pragma unroll
    for (int r = 0; r < 4; r++) {
      float v = acc[t][r];
      C[(size_t)(row0 + quad * 4 + r) * Nf + col0 + t * 16 + l16] = v;
      zone[(t * 16 + l16) * 36 + wave * 16 + quad * 4 + r] = f2bf(v);
    }
  }
  __syncthreads();
  // HTt chunk for this block: [row0blk/32][col0..col0+nf*16][0..32): nf*16 f-values x 16 dwords
  unsigned* dst = (unsigned*)(HTt + (size_t)(blockIdx.x) * Nf * 32 + (size_t)col0 * 32);
  const unsigned* zsrc = (const unsigned*)zone;
  int total = nf * 256;                            // dwords (nf*16 f-rows x 32 shorts each)
  for (int idx = threadIdx.x; idx < total; idx += 128) {
    int f = idx >> 4, jp = idx & 15;
    dst[idx] = zsrc[f * 18 + jp];
  }
}

// ---- src/tgt + Ev/Gv: per-row dots of H with a[:f], a[f:]; exp with constant TM ----
__global__ void gemv_srctgt(const float* __restrict__ H, const float* __restrict__ a,
                            float* __restrict__ src, float* __restrict__ Ev,
                            float* __restrict__ Gv, int f) {
  int row = blockIdx.x * 4 + (threadIdx.x >> 6);
  int lane = threadIdx.x & 63;
  float s = 0.f, t = 0.f;
  for (int k = lane; k < f; k += 64) {
    float h = H[(size_t)row * f + k];
    s += h * a[k];
    t += h * a[f + k];
  }
#pragma unroll
  for (int off = 32; off; off >>= 1) { s += __shfl_down(s, off); t += __shfl_down(t, off); }
  if (lane == 0) {
    src[row] = s;
    Ev[row] = __expf(t - TMC);
    Gv[row] = __expf(0.2f * (t - TMC));
  }
}

// ---- pass1b: masked denom via max(P*Ej,Q*Gj); writes Av,Bv directly; no exp in loop ----
__global__ void pass1b(const unsigned long long* __restrict__ bits, const float* __restrict__ src,
                       const float* __restrict__ Ev, const float* __restrict__ Gv,
                       float* __restrict__ Av, float* __restrict__ Bv) {
  int row = blockIdx.x * 4 + (threadIdx.x >> 6);
  int lane = threadIdx.x & 63;
  float sp = src[row] + TMC;                       // s' = s + TM
  float m = sp > 0.f ? sp : 0.2f * sp;             // lrelu(s') >= lrelu(s+t_j) since t_j <= TM
  float P = __expf(sp - m), Q = __expf(0.2f * sp - m);
  const unsigned long long* brow = bits + (size_t)row * 64;
  float lsum = 0.f;
  for (int k = 0; k < 64; k++) {
    unsigned long long w = brow[k];
    float v = fmaxf(P * Ev[k * 64 + lane], Q * Gv[k * 64 + lane]);  // = exp(lrelu(s+t_j)-m)
    lsum += ((w >> lane) & 1ull) ? v : 0.f;
  }
#pragma unroll
  for (int off = 32; off; off >>= 1) lsum += __shfl_xor(lsum, off);
  if (lane == 0) {
    float inv = 1.0f / lsum;
    Av[row] = P * inv;                             // = exp(s' - c), c = m + ln(lsum)
    Bv[row] = Q * inv;
  }
}

// ---- pass2p: OUT = P @ H, software-pipelined, bf16 MFMA, no LDS/barriers/atomics ----
// 4 waves/block; wave w owns rows [i0+w*16, ...+16) completely. Ping-pong register buffers:
// loads for iteration k+1 are issued before compute of iteration k (hides L2 latency).
// grid (64, fc, js); js>1 -> per-z partials reduced deterministically afterwards.
template<int NF>
__global__ __launch_bounds__(256) void pass2p(const unsigned* __restrict__ adjW,
                                              const float* __restrict__ Av,
                                              const float* __restrict__ Bv,
                                              const float* __restrict__ Ev,
                                              const float* __restrict__ Gv,
                                              const unsigned short* __restrict__ HTt,
                                              float* __restrict__ out, int F, int js) {
  const int W = NF * 16;
  int lane = threadIdx.x & 63, wave = threadIdx.x >> 6;
  int quad = lane >> 4, l16 = lane & 15;
  int i0 = blockIdx.x * 64 + wave * 16;            // this wave's 16 rows
  int fc0 = blockIdx.y * W;
  const size_t F32 = (size_t)F * 32;
  int i = i0 + l16;
  float Ai = Av[i], Bi = Bv[i];
  const unsigned* arow = adjW + (size_t)i * 128;   // 128 adjacency dwords per row
  v4f acc[NF];
#pragma unroll
  for (int t = 0; t < NF; t++) acc[t] = (v4f){0.f, 0.f, 0.f, 0.f};

  struct Buf { v8s bfr[NF]; float4 e0, e1, g0, g1; unsigned bw; };
  Buf b0, b1;

  auto LOAD = [&](Buf& b, int j0) {
    int jb = j0 + quad * 8;
    const unsigned short* bp =
        HTt + (size_t)(j0 >> 5) * F32 + (size_t)(fc0 + l16) * 32 + quad * 8;
#pragma unroll
    for (int t = 0; t < NF; t++) b.bfr[t] = *(const v8s*)(bp + t * 512);
    b.e0 = *(const float4*)(Ev + jb); b.e1 = *(const float4*)(Ev + jb + 4);
    b.g0 = *(const float4*)(Gv + jb); b.g1 = *(const float4*)(Gv + jb + 4);
    b.bw = arow[j0 >> 5];
  };
  auto COMP = [&](const Buf& b) {
    float ev[8] = {b.e0.x, b.e0.y, b.e0.z, b.e0.w, b.e1.x, b.e1.y, b.e1.z, b.e1.w};
    float gv[8] = {b.g0.x, b.g0.y, b.g0.z, b.g0.w, b.g1.x, b.g1.y, b.g1.z, b.g1.w};
    unsigned bb = b.bw >> (quad * 8);
    float w[8];
#pragma unroll
    for (int jj = 0; jj < 8; jj++) {
      float v = fmaxf(Ai * ev[jj], Bi * gv[jj]);   // exp(lrelu(s+t)-c), factorized
      w[jj] = ((bb >> jj) & 1u) ? v : 0.f;
    }
    union { v8s s; __hip_bfloat162 h[4]; } ua;
#pragma unroll
    for (int p = 0; p < 4; p++)
      ua.h[p] = __float22bfloat162_rn(make_float2(w[2 * p], w[2 * p + 1]));
#pragma unroll
    for (int t = 0; t < NF; t++)
      acc[t] = __builtin_amdgcn_mfma_f32_16x16x32_bf16(ua.s, b.bfr[t], acc[t], 0, 0, 0);
  };

  int jrange = NROWS / js;                         // iteration count jrange/32 is even (>=16)
  int jstart = blockIdx.z * jrange;
  int jend = jstart + jrange;
  LOAD(b0, jstart);
  int j0 = jstart;
  for (; j0 + 64 < jend; j0 += 64) {
    LOAD(b1, j0 + 32);
    COMP(b0);
    LOAD(b0, j0 + 64);
    COMP(b1);
  }
  LOAD(b1, j0 + 32);
  COMP(b0);
  COMP(b1);

  // direct store: this wave exclusively owns its 16 rows (C/D: row=quad*4+r, col=l16)
  size_t zoff = (size_t)blockIdx.z * NROWS;        // js==1: 0
#pragma unroll
  for (int t = 0; t < NF; t++)
#pragma unroll
    for (int r = 0; r < 4; r++)
      out[(zoff + i0 + quad * 4 + r) * F + fc0 + t * 16 + l16] = acc[t][r];
}

// ---- deterministic cross-z reduce for js>1 partials ----
__global__ void reduce_js(const float* __restrict__ part, float* __restrict__ out, int n, int js) {
  int i = blockIdx.x * 256 + threadIdx.x;
  if (i < n) {
    float s = part[i];
    for (int z = 1; z < js; z++) s += part[(size_t)z * n + i];
    out[i] = s;
  }
}

static void launch_pass2(int NF, dim3 grid, const unsigned* adjW, const float* Av, const float* Bv,
                         const float* Ev, const float* Gv, const unsigned short* HTt, float* out,
                         int F, int js, hipStream_t stream) {
  switch (NF) {
    case 4: pass2p<4><<<grid, 256, 0, stream>>>(adjW, Av, Bv, Ev, Gv, HTt, out, F, js); break;
    default: pass2p<1><<<grid, 256, 0, stream>>>(adjW, Av, Bv, Ev, Gv, HTt, out, F, js); break;
  }
}

extern "C" void kernel_launch(void* const* d_in, const int* in_sizes, int n_in,
                              void* d_out, int out_size, void* d_ws, size_t ws_size,
                              hipStream_t stream) {
  static const int fin[8]  = {512, 256, 128, 64, 16, 64, 128, 256};
  static const int fout[8] = {256, 128, 64, 16, 64, 128, 256, 512};

  const float* x = (const float*)d_in[0];
  const int* adj = (const int*)d_in[1];
  char* ws = (char*)d_ws;
  unsigned long long* bits = (unsigned long long*)(ws);                 // 2 MB
  unsigned short* WTall = (unsigned short*)(ws + (2u << 20));           // <1 MB, all layers
  float* H            = (float*)(ws + (6u << 20));                      // 8 MB max
  unsigned short* HTt = (unsigned short*)(ws + (14u << 20));            // 4 MB max
  float* srcv = (float*)(ws + (19u << 20));
  float* Av   = (float*)(ws + (19u << 20) + 49152);
  float* Bv   = (float*)(ws + (19u << 20) + 65536);
  float* Ev   = (float*)(ws + (19u << 20) + 81920);
  float* Gv   = (float*)(ws + (19u << 20) + 98304);
  float* o5   = (float*)(ws + (20u << 20));                             // 1 MB
  float* o6   = (float*)(ws + (21u << 20));                             // 2 MB
  float* o7   = (float*)(ws + (23u << 20));                             // 4 MB
  // js>1 partials (<=8MB) alias H: H's last reader (gemv_srctgt) runs before pass2p,
  // and gemm_xw of the next layer rewrites H afterwards (stream-ordered).
  float* part = H;

  float* outp = (float*)d_out;
  float* xbar = outp;
  float* h1 = outp + (size_t)NROWS * 512;
  float* h2 = h1 + (size_t)NROWS * 256;
  float* h3 = h2 + (size_t)NROWS * 128;
  float* h4 = h3 + (size_t)NROWS * 64;

  float* louts[8] = {h1, h2, h3, h4, o5, o6, o7, xbar};
  const float* lins[8] = {x, h1, h2, h3, h4, o5, o6, o7};

  unsigned short* WT[8];
  { size_t off = 0;
    for (int t = 0; t < 8; t++) { WT[t] = WTall + off; off += (size_t)fin[t] * fout[t]; } }

  pack_adj<<<dim3(4096), dim3(256), 0, stream>>>(adj, bits);

  WTArgs wa;
  for (int t = 0; t < 8; t++) {
    wa.src[t] = (const float*)d_in[2 + 2 * t];
    wa.dst[t] = WT[t];
    wa.K[t] = fin[t];
    wa.F[t] = fout[t];
  }
  transpose_w<<<dim3(16, 16, 8), dim3(32, 8), 0, stream>>>(wa);

  for (int t = 0; t < 8; t++) {
    int K = fin[t], F = fout[t];
    const float* At = (const float*)d_in[3 + 2 * t];
    const float* Xin = lins[t];
    float* Ot = louts[t];

    // grid (64, fc, js) = 512 blocks for every layer; partials capped at 8MB
    int NF = F >= 64 ? 4 : 1;                      // 512..64 -> 4, 16 -> 1
    int fc = F / (16 * NF);                        // 512->8, 256->4, 128->2, 64->1, 16->1
    int js = (F == 512) ? 1 : (F == 256 ? 2 : (F == 128 ? 4 : 8));

    gemm_xw<<<dim3(128, (F + 63) / 64), dim3(128), 0, stream>>>(Xin, WT[t], H, HTt, K, F);
    gemv_srctgt<<<dim3(1024), dim3(256), 0, stream>>>(H, At, srcv, Ev, Gv, F);
    pass1b<<<dim3(1024), dim3(256), 0, stream>>>(bits, srcv, Ev, Gv, Av, Bv);
    float* p2out = (js > 1) ? part : Ot;
    launch_pass2(NF, dim3(64, fc, js), (const unsigned*)bits, Av, Bv, Ev, Gv, HTt, p2out, F, js,
                 stream);
    if (js > 1)
      reduce_js<<<dim3((NROWS * F + 255) / 256), dim3(256), 0, stream>>>(part, Ot, NROWS * F, js);
  }
}

// Round 10
// 653.483 us; speedup vs baseline: 1.1176x; 1.1176x over previous
//
#include <hip/hip_runtime.h>
#include <hip/hip_bf16.h>

// GAE: 8 stacked GAT layers on N=4096 nodes, dims 512->256->128->64->16->64->128->256->512.
// Outputs (concat in d_out): x_bar[4096*512], h1[4096*256], h2[4096*128], h3[4096*64], h4[4096*16].
//
// Per layer:
//   H = X @ W                      (bf16 MFMA GEMM, fp32 accum; HTt bf16 j-tiled layout written
//                                   directly from the GEMM epilogue via LDS)
//   src = H @ a[:f], tgt = H @ a[f:]; Ev=exp(t-TM), Gv=exp(0.2(t-TM)) with CONSTANT TM=12
//     (factorization exact for any upper bound TM >= max tgt)
//   pass1b: lsum_i = sum_{j in N(i)} max(P_i*Ev_j, Q_i*Gv_j); Av=P/lsum, Bv=Q/lsum (no exp in loop)
//   pass2f: OUT[i,:] = sum_j max(Av_i*Ev_j, Bv_i*Gv_j) * H[j,:]  == softmax(lrelu masked) @ H
// pass2f (R5 structure, best measured): 4 waves/block, 32-row i-tile (2 acc tiles/wave), waves
// split the block's j-range 4 ways, LDS combine in FIXED wave order. NEW: every layer j-splits
// across blockIdx.z so grid = 1024 blocks (4 blocks/CU, 16 waves/CU). z=0 writes output
// directly; z>0 writes partial slabs (aliased into dead H buffer, <=8MB) folded by a
// deterministic reduce_add. NO atomics, no memset -> bitwise deterministic.
// HTt[j/32][f][j%32] keeps B-fragment loads contiguous 1KB/wave.
// adj packed to a 2MB bitmask once, reused by all 8 layers.

#define NROWS 4096
#define TMC 12.0f

typedef __attribute__((ext_vector_type(8))) short v8s;
typedef __attribute__((ext_vector_type(4))) float v4f;

__device__ inline unsigned short f2bf(float x) {
  union { float f; unsigned u; } v; v.f = x;
  unsigned r = v.u + 0x7fffu + ((v.u >> 16) & 1u);   // RNE
  return (unsigned short)(r >> 16);
}

// ---- pack adj (int32 0/1) -> bitmask, 64 uint64 words per row ----
__global__ void pack_adj(const int* __restrict__ adj, unsigned long long* __restrict__ bits) {
  int row = blockIdx.x;
  int lane = threadIdx.x & 63, wave = threadIdx.x >> 6;
  for (int w = wave; w < 64; w += 4) {
    unsigned long long m = __ballot(adj[(size_t)row * NROWS + w * 64 + lane] > 0);
    if (lane == 0) bits[row * 64 + w] = m;
  }
}

// ---- batched W transpose: fp32 [K][F] -> bf16 [F][K], all 8 layers in one launch ----
struct WTArgs { const float* src[8]; unsigned short* dst[8]; int K[8]; int F[8]; };
__global__ void transpose_w(WTArgs A) {
  int z = blockIdx.z;
  const float* in = A.src[z];
  unsigned short* out = A.dst[z];
  int R = A.K[z], C = A.F[z];
  __shared__ unsigned short tile[32][33];
  int c0 = blockIdx.x * 32, r0 = blockIdx.y * 32;
  if (c0 >= C || r0 >= R) return;          // block-uniform: safe before barrier
#pragma unroll
  for (int dy = 0; dy < 32; dy += 8) {
    int r = r0 + threadIdx.y + dy, c = c0 + threadIdx.x;
    if (r < R && c < C) tile[threadIdx.y + dy][threadIdx.x] = f2bf(in[(size_t)r * C + c]);
  }
  __syncthreads();
#pragma unroll
  for (int dy = 0; dy < 32; dy += 8) {
    int c = c0 + threadIdx.y + dy, r = r0 + threadIdx.x;
    if (r < R && c < C) out[(size_t)c * R + r] = tile[threadIdx.x][threadIdx.y + dy];
  }
}

// ---- C[4096][Nf] = A_f32[4096][K] x B[K][Nf], B given as BT[Nf][K] bf16 ----
// 2 waves/block, 16 rows each; grid (128, ceil(Nf/64)).
// Epilogue also writes HTt[j/32][f][j%32] bf16 directly (LDS-staged) -> no separate transpose.
__global__ __launch_bounds__(128) void gemm_xw(const float* __restrict__ A,
                                               const unsigned short* __restrict__ BT,
                                               float* __restrict__ C,
                                               unsigned short* __restrict__ HTt,
                                               int K, int Nf) {
  __shared__ unsigned short zone[64 * 36];         // [f_local][j_local], stride 36 vs banks
  int lane = threadIdx.x & 63, wave = threadIdx.x >> 6;
  int quad = lane >> 4, l16 = lane & 15;
  int row0 = blockIdx.x * 32 + wave * 16;
  int col0 = blockIdx.y * 64;
  int nf = Nf - col0; nf = nf > 64 ? 4 : (nf + 15) / 16;
  v4f acc[4] = {{0.f,0.f,0.f,0.f},{0.f,0.f,0.f,0.f},{0.f,0.f,0.f,0.f},{0.f,0.f,0.f,0.f}};
  for (int k0 = 0; k0 < K; k0 += 32) {
    int kk = k0 + quad * 8;
    v8s a = {0,0,0,0,0,0,0,0};
    if (kk < K) {
      float4 f0 = *(const float4*)(A + (size_t)(row0 + l16) * K + kk);
      float4 f1 = *(const float4*)(A + (size_t)(row0 + l16) * K + kk + 4);
      union { v8s s; __hip_bfloat162 h[4]; } ua;
      ua.h[0] = __float22bfloat162_rn(make_float2(f0.x, f0.y));
      ua.h[1] = __float22bfloat162_rn(make_float2(f0.z, f0.w));
      ua.h[2] = __float22bfloat162_rn(make_float2(f1.x, f1.y));
      ua.h[3] = __float22bfloat162_rn(make_float2(f1.z, f1.w));
      a = ua.s;
    }
    for (int t = 0; t < nf; t++) {
      v8s b = {0,0,0,0,0,0,0,0};
      if (kk < K) b = *(const v8s*)(BT + (size_t)(col0 + t * 16 + l16) * K + kk);
      acc[t] = __builtin_amdgcn_mfma_f32_16x16x32_bf16(a, b, acc[t], 0, 0, 0);
    }
  }
  for (int t = 0; t < nf; t++) {
#pragma unroll
    for (int r = 0; r < 4; r++) {
      float v = acc[t][r];
      C[(size_t)(row0 + quad * 4 + r) * Nf + col0 + t * 16 + l16] = v;
      zone[(t * 16 + l16) * 36 + wave * 16 + quad * 4 + r] = f2bf(v);
    }
  }
  __syncthreads();
  // HTt chunk for this block: [row0blk/32][col0..col0+nf*16][0..32): nf*16 f-values x 16 dwords
  unsigned* dst = (unsigned*)(HTt + (size_t)(blockIdx.x) * Nf * 32 + (size_t)col0 * 32);
  const unsigned* zsrc = (const unsigned*)zone;
  int total = nf * 256;                            // dwords (nf*16 f-rows x 32 shorts each)
  for (int idx = threadIdx.x; idx < total; idx += 128) {
    int f = idx >> 4, jp = idx & 15;
    dst[idx] = zsrc[f * 18 + jp];
  }
}

// ---- src/tgt + Ev/Gv: per-row dots of H with a[:f], a[f:]; exp with constant TM ----
__global__ void gemv_srctgt(const float* __restrict__ H, const float* __restrict__ a,
                            float* __restrict__ src, float* __restrict__ Ev,
                            float* __restrict__ Gv, int f) {
  int row = blockIdx.x * 4 + (threadIdx.x >> 6);
  int lane = threadIdx.x & 63;
  float s = 0.f, t = 0.f;
  for (int k = lane; k < f; k += 64) {
    float h = H[(size_t)row * f + k];
    s += h * a[k];
    t += h * a[f + k];
  }
#pragma unroll
  for (int off = 32; off; off >>= 1) { s += __shfl_down(s, off); t += __shfl_down(t, off); }
  if (lane == 0) {
    src[row] = s;
    Ev[row] = __expf(t - TMC);
    Gv[row] = __expf(0.2f * (t - TMC));
  }
}

// ---- pass1b: masked denom via max(P*Ej,Q*Gj); writes Av,Bv directly; no exp in loop ----
__global__ void pass1b(const unsigned long long* __restrict__ bits, const float* __restrict__ src,
                       const float* __restrict__ Ev, const float* __restrict__ Gv,
                       float* __restrict__ Av, float* __restrict__ Bv) {
  int row = blockIdx.x * 4 + (threadIdx.x >> 6);
  int lane = threadIdx.x & 63;
  float sp = src[row] + TMC;                       // s' = s + TM
  float m = sp > 0.f ? sp : 0.2f * sp;             // lrelu(s') >= lrelu(s+t_j) since t_j <= TM
  float P = __expf(sp - m), Q = __expf(0.2f * sp - m);
  const unsigned long long* brow = bits + (size_t)row * 64;
  float lsum = 0.f;
  for (int k = 0; k < 64; k++) {
    unsigned long long w = brow[k];
    float v = fmaxf(P * Ev[k * 64 + lane], Q * Gv[k * 64 + lane]);  // = exp(lrelu(s+t_j)-m)
    lsum += ((w >> lane) & 1ull) ? v : 0.f;
  }
#pragma unroll
  for (int off = 32; off; off >>= 1) lsum += __shfl_xor(lsum, off);
  if (lane == 0) {
    float inv = 1.0f / lsum;
    Av[row] = P * inv;                             // = exp(s' - c), c = m + ln(lsum)
    Bv[row] = Q * inv;
  }
}

// ---- pass2f: OUT = P @ H, P synthesized on the fly (no exp), bf16 MFMA ----
// block: 4 waves, 32-row i-tile (2 acc tiles/wave), waves split the block's j-range 4 ways.
// B-fragments (HTt, contiguous 1KB/wave) loaded once per j-block, reused over 2 i-tiles.
// Epilogue: LDS combine in FIXED wave order (no atomics), direct coalesced store.
// grid (128, fc, js): z=0 stores to out, z>0 stores to part slab z-1 (reduced afterwards).
template<int NF>
__global__ __launch_bounds__(256) void pass2f(const unsigned* __restrict__ adjW,
                                              const float* __restrict__ Av,
                                              const float* __restrict__ Bv,
                                              const float* __restrict__ Ev,
                                              const float* __restrict__ Gv,
                                              const unsigned short* __restrict__ HTt,
                                              float* __restrict__ out,
                                              float* __restrict__ part, int F, int js) {
  const int W = NF * 16, Wp = W + 4;               // +4 pad: kills quad-aliasing bank conflicts
  __shared__ float zone[32 * Wp];
  int lane = threadIdx.x & 63, wave = threadIdx.x >> 6;
  int quad = lane >> 4, l16 = lane & 15;
  int i0 = blockIdx.x * 32;
  int fc0 = blockIdx.y * W;
  const size_t F32 = (size_t)F * 32;
  int jrange = NROWS / js;
  int jlen = jrange / 4;
  int jstart = blockIdx.z * jrange + wave * jlen;

  float Ai[2], Bi[2];
  const unsigned* arow[2];
#pragma unroll
  for (int ni = 0; ni < 2; ni++) {
    int i = i0 + ni * 16 + l16;
    Ai[ni] = Av[i]; Bi[ni] = Bv[i];
    arow[ni] = adjW + (size_t)i * 128;             // 128 adjacency dwords per row
  }
  v4f acc[2][NF];
#pragma unroll
  for (int ni = 0; ni < 2; ni++)
#pragma unroll
    for (int t = 0; t < NF; t++) acc[ni][t] = (v4f){0.f, 0.f, 0.f, 0.f};

  for (int j0 = jstart; j0 < jstart + jlen; j0 += 32) {
    int jb = j0 + quad * 8;
    float4 e0 = *(const float4*)(Ev + jb), e1 = *(const float4*)(Ev + jb + 4);
    float4 g0 = *(const float4*)(Gv + jb), g1 = *(const float4*)(Gv + jb + 4);
    float ev[8] = {e0.x, e0.y, e0.z, e0.w, e1.x, e1.y, e1.z, e1.w};
    float gv[8] = {g0.x, g0.y, g0.z, g0.w, g1.x, g1.y, g1.z, g1.w};
    // B-fragments: wave reads contiguous 1KB per t; shared across the 2 i-tiles
    const unsigned short* bp = HTt + (size_t)(j0 >> 5) * F32 + (size_t)(fc0 + l16) * 32 + quad * 8;
    v8s bfr[NF];
#pragma unroll
    for (int t = 0; t < NF; t++) bfr[t] = *(const v8s*)(bp + t * 512);
#pragma unroll
    for (int ni = 0; ni < 2; ni++) {
      unsigned bb = arow[ni][j0 >> 5] >> (quad * 8);
      float w[8];
#pragma unroll
      for (int jj = 0; jj < 8; jj++) {
        float v = fmaxf(Ai[ni] * ev[jj], Bi[ni] * gv[jj]);   // exp(lrelu(s+t)-c), factorized
        w[jj] = ((bb >> jj) & 1u) ? v : 0.f;
      }
      union { v8s s; __hip_bfloat162 h[4]; } ua;
#pragma unroll
      for (int p = 0; p < 4; p++)
        ua.h[p] = __float22bfloat162_rn(make_float2(w[2 * p], w[2 * p + 1]));
#pragma unroll
      for (int t = 0; t < NF; t++)
        acc[ni][t] = __builtin_amdgcn_mfma_f32_16x16x32_bf16(ua.s, bfr[t], acc[ni][t], 0, 0, 0);
    }
  }

  // deterministic combine: waves add into zone in fixed order
  for (int w = 0; w < 4; w++) {
    if (wave == w) {
#pragma unroll
      for (int ni = 0; ni < 2; ni++)
#pragma unroll
        for (int t = 0; t < NF; t++)
#pragma unroll
          for (int r = 0; r < 4; r++) {
            int idx = (ni * 16 + quad * 4 + r) * Wp + t * 16 + l16;
            if (w == 0) zone[idx] = acc[ni][t][r];
            else        zone[idx] += acc[ni][t][r];
          }
    }
    __syncthreads();
  }
  float* dst = (blockIdx.z == 0) ? out : part + (size_t)(blockIdx.z - 1) * NROWS * F;
  for (int idx = threadIdx.x; idx < 32 * W; idx += 256) {
    int rrow = idx / W, ccol = idx - rrow * W;
    dst[(size_t)(i0 + rrow) * F + fc0 + ccol] = zone[rrow * Wp + ccol];
  }
}

// ---- deterministic cross-z fold: out[i] += sum of js-1 partial slabs ----
__global__ void reduce_add(const float* __restrict__ part, float* __restrict__ out, int n,
                           int nslab) {
  int i = blockIdx.x * 256 + threadIdx.x;
  if (i < n) {
    float s = out[i];
    for (int z = 0; z < nslab; z++) s += part[(size_t)z * n + i];
    out[i] = s;
  }
}

static void launch_pass2(int NF, dim3 grid, const unsigned* adjW, const float* Av, const float* Bv,
                         const float* Ev, const float* Gv, const unsigned short* HTt, float* out,
                         float* part, int F, int js, hipStream_t stream) {
  switch (NF) {
    case 8: pass2f<8><<<grid, 256, 0, stream>>>(adjW, Av, Bv, Ev, Gv, HTt, out, part, F, js); break;
    case 4: pass2f<4><<<grid, 256, 0, stream>>>(adjW, Av, Bv, Ev, Gv, HTt, out, part, F, js); break;
    case 2: pass2f<2><<<grid, 256, 0, stream>>>(adjW, Av, Bv, Ev, Gv, HTt, out, part, F, js); break;
    default: pass2f<1><<<grid, 256, 0, stream>>>(adjW, Av, Bv, Ev, Gv, HTt, out, part, F, js); break;
  }
}

extern "C" void kernel_launch(void* const* d_in, const int* in_sizes, int n_in,
                              void* d_out, int out_size, void* d_ws, size_t ws_size,
                              hipStream_t stream) {
  static const int fin[8]  = {512, 256, 128, 64, 16, 64, 128, 256};
  static const int fout[8] = {256, 128, 64, 16, 64, 128, 256, 512};

  const float* x = (const float*)d_in[0];
  const int* adj = (const int*)d_in[1];
  char* ws = (char*)d_ws;
  unsigned long long* bits = (unsigned long long*)(ws);                 // 2 MB
  unsigned short* WTall = (unsigned short*)(ws + (2u << 20));           // <1 MB, all layers
  float* H            = (float*)(ws + (6u << 20));                      // 8 MB max
  unsigned short* HTt = (unsigned short*)(ws + (14u << 20));            // 4 MB max
  float* srcv = (float*)(ws + (19u << 20));
  float* Av   = (float*)(ws + (19u << 20) + 49152);
  float* Bv   = (float*)(ws + (19u << 20) + 65536);
  float* Ev   = (float*)(ws + (19u << 20) + 81920);
  float* Gv   = (float*)(ws + (19u << 20) + 98304);
  float* o5   = (float*)(ws + (20u << 20));                             // 1 MB
  float* o6   = (float*)(ws + (21u << 20));                             // 2 MB
  float* o7   = (float*)(ws + (23u << 20));                             // 4 MB
  // partial slabs ((js-1)*N*F*4 <= 8MB) alias H: H's last reader (gemv_srctgt/pass1b) runs
  // before pass2f; next layer's gemm_xw rewrites H afterwards (stream-ordered).
  float* part = H;

  float* outp = (float*)d_out;
  float* xbar = outp;
  float* h1 = outp + (size_t)NROWS * 512;
  float* h2 = h1 + (size_t)NROWS * 256;
  float* h3 = h2 + (size_t)NROWS * 128;
  float* h4 = h3 + (size_t)NROWS * 64;

  float* louts[8] = {h1, h2, h3, h4, o5, o6, o7, xbar};
  const float* lins[8] = {x, h1, h2, h3, h4, o5, o6, o7};

  unsigned short* WT[8];
  { size_t off = 0;
    for (int t = 0; t < 8; t++) { WT[t] = WTall + off; off += (size_t)fin[t] * fout[t]; } }

  pack_adj<<<dim3(4096), dim3(256), 0, stream>>>(adj, bits);

  WTArgs wa;
  for (int t = 0; t < 8; t++) {
    wa.src[t] = (const float*)d_in[2 + 2 * t];
    wa.dst[t] = WT[t];
    wa.K[t] = fin[t];
    wa.F[t] = fout[t];
  }
  transpose_w<<<dim3(16, 16, 8), dim3(32, 8), 0, stream>>>(wa);

  for (int t = 0; t < 8; t++) {
    int K = fin[t], F = fout[t];
    const float* At = (const float*)d_in[3 + 2 * t];
    const float* Xin = lins[t];
    float* Ot = louts[t];

    // grid (128, fc, js) = 1024 blocks (4/CU, 16 waves/CU) for every layer
    int NF = F >= 512 ? 8 : (F >= 256 ? 4 : (F >= 128 ? 2 : 1));
    int fc = F / (16 * NF);                        // 512/256/128/64 -> 4, 16 -> 1
    int js = (F == 16) ? 8 : 2;                    // partial slabs (js-1)*N*F*4 <= 8MB

    gemm_xw<<<dim3(128, (F + 63) / 64), dim3(128), 0, stream>>>(Xin, WT[t], H, HTt, K, F);
    gemv_srctgt<<<dim3(1024), dim3(256), 0, stream>>>(H, At, srcv, Ev, Gv, F);
    pass1b<<<dim3(1024), dim3(256), 0, stream>>>(bits, srcv, Ev, Gv, Av, Bv);
    launch_pass2(NF, dim3(128, fc, js), (const unsigned*)bits, Av, Bv, Ev, Gv, HTt, Ot, part, F,
                 js, stream);
    reduce_add<<<dim3((NROWS * F + 255) / 256), dim3(256), 0, stream>>>(part, Ot, NROWS * F,
                                                                        js - 1);
  }
}

// Round 11
// 574.825 us; speedup vs baseline: 1.2705x; 1.1368x over previous
//
#include <hip/hip_runtime.h>
#include <hip/hip_bf16.h>

// GAE: 8 stacked GAT layers on N=4096 nodes, dims 512->256->128->64->16->64->128->256->512.
// Outputs (concat in d_out): x_bar[4096*512], h1[4096*256], h2[4096*128], h3[4096*64], h4[4096*16].
//
// Per layer:
//   H = X @ W                      (bf16 MFMA GEMM, fp32 accum; HTt bf16 j-tiled layout written
//                                   directly from the GEMM epilogue via LDS)
//   src = H @ a[:f], tgt = H @ a[f:]; Ev=exp(t-TM), Gv=exp(0.2(t-TM)) with CONSTANT TM=12
//     (factorization exact for any upper bound TM >= max tgt)
//   pass1b: lsum_i = sum_{j in N(i)} max(P_i*Ev_j, Q_i*Gv_j); Av=P/lsum, Bv=Q/lsum (no exp in loop)
//   pass2f: OUT[i,:] = sum_j max(Av_i*Ev_j, Bv_i*Gv_j) * H[j,:]  == softmax(lrelu masked) @ H
// pass2f: 4 waves/block, 32-row i-tile (2 acc tiles/wave), waves split the block's j-range
// 4 ways, LDS combine in FIXED wave order. NF=8 (128-col chunks) for all F>=128 minimizes
// fc replicas of the per-edge A-build (the measured per-CU throughput wall). Grid = 512 blocks
// (2/CU) per layer via j-splitting; z>0 partial slabs (aliased into dead H buffer) folded by a
// deterministic reduce_add. NO atomics, no memset -> bitwise deterministic.
// HTt[j/32][f][j%32] keeps B-fragment loads contiguous 1KB/wave.
// adj packed to a 2MB bitmask once, reused by all 8 layers.

#define NROWS 4096
#define TMC 12.0f

typedef __attribute__((ext_vector_type(8))) short v8s;
typedef __attribute__((ext_vector_type(4))) float v4f;

__device__ inline unsigned short f2bf(float x) {
  union { float f; unsigned u; } v; v.f = x;
  unsigned r = v.u + 0x7fffu + ((v.u >> 16) & 1u);   // RNE
  return (unsigned short)(r >> 16);
}

// ---- pack adj (int32 0/1) -> bitmask, 64 uint64 words per row ----
__global__ void pack_adj(const int* __restrict__ adj, unsigned long long* __restrict__ bits) {
  int row = blockIdx.x;
  int lane = threadIdx.x & 63, wave = threadIdx.x >> 6;
  for (int w = wave; w < 64; w += 4) {
    unsigned long long m = __ballot(adj[(size_t)row * NROWS + w * 64 + lane] > 0);
    if (lane == 0) bits[row * 64 + w] = m;
  }
}

// ---- batched W transpose: fp32 [K][F] -> bf16 [F][K], all 8 layers in one launch ----
struct WTArgs { const float* src[8]; unsigned short* dst[8]; int K[8]; int F[8]; };
__global__ void transpose_w(WTArgs A) {
  int z = blockIdx.z;
  const float* in = A.src[z];
  unsigned short* out = A.dst[z];
  int R = A.K[z], C = A.F[z];
  __shared__ unsigned short tile[32][33];
  int c0 = blockIdx.x * 32, r0 = blockIdx.y * 32;
  if (c0 >= C || r0 >= R) return;          // block-uniform: safe before barrier
#pragma unroll
  for (int dy = 0; dy < 32; dy += 8) {
    int r = r0 + threadIdx.y + dy, c = c0 + threadIdx.x;
    if (r < R && c < C) tile[threadIdx.y + dy][threadIdx.x] = f2bf(in[(size_t)r * C + c]);
  }
  __syncthreads();
#pragma unroll
  for (int dy = 0; dy < 32; dy += 8) {
    int c = c0 + threadIdx.y + dy, r = r0 + threadIdx.x;
    if (r < R && c < C) out[(size_t)c * R + r] = tile[threadIdx.x][threadIdx.y + dy];
  }
}

// ---- C[4096][Nf] = A_f32[4096][K] x B[K][Nf], B given as BT[Nf][K] bf16 ----
// 2 waves/block, 16 rows each; grid (128, ceil(Nf/64)).
// Epilogue also writes HTt[j/32][f][j%32] bf16 directly (LDS-staged) -> no separate transpose.
__global__ __launch_bounds__(128) void gemm_xw(const float* __restrict__ A,
                                               const unsigned short* __restrict__ BT,
                                               float* __restrict__ C,
                                               unsigned short* __restrict__ HTt,
                                               int K, int Nf) {
  __shared__ unsigned short zone[64 * 36];         // [f_local][j_local], stride 36 vs banks
  int lane = threadIdx.x & 63, wave = threadIdx.x >> 6;
  int quad = lane >> 4, l16 = lane & 15;
  int row0 = blockIdx.x * 32 + wave * 16;
  int col0 = blockIdx.y * 64;
  int nf = Nf - col0; nf = nf > 64 ? 4 : (nf + 15) / 16;
  v4f acc[4] = {{0.f,0.f,0.f,0.f},{0.f,0.f,0.f,0.f},{0.f,0.f,0.f,0.f},{0.f,0.f,0.f,0.f}};
  for (int k0 = 0; k0 < K; k0 += 32) {
    int kk = k0 + quad * 8;
    v8s a = {0,0,0,0,0,0,0,0};
    if (kk < K) {
      float4 f0 = *(const float4*)(A + (size_t)(row0 + l16) * K + kk);
      float4 f1 = *(const float4*)(A + (size_t)(row0 + l16) * K + kk + 4);
      union { v8s s; __hip_bfloat162 h[4]; } ua;
      ua.h[0] = __float22bfloat162_rn(make_float2(f0.x, f0.y));
      ua.h[1] = __float22bfloat162_rn(make_float2(f0.z, f0.w));
      ua.h[2] = __float22bfloat162_rn(make_float2(f1.x, f1.y));
      ua.h[3] = __float22bfloat162_rn(make_float2(f1.z, f1.w));
      a = ua.s;
    }
    for (int t = 0; t < nf; t++) {
      v8s b = {0,0,0,0,0,0,0,0};
      if (kk < K) b = *(const v8s*)(BT + (size_t)(col0 + t * 16 + l16) * K + kk);
      acc[t] = __builtin_amdgcn_mfma_f32_16x16x32_bf16(a, b, acc[t], 0, 0, 0);
    }
  }
  for (int t = 0; t < nf; t++) {
#pragma unroll
    for (int r = 0; r < 4; r++) {
      float v = acc[t][r];
      C[(size_t)(row0 + quad * 4 + r) * Nf + col0 + t * 16 + l16] = v;
      zone[(t * 16 + l16) * 36 + wave * 16 + quad * 4 + r] = f2bf(v);
    }
  }
  __syncthreads();
  // HTt chunk for this block: [row0blk/32][col0..col0+nf*16][0..32): nf*16 f-values x 16 dwords
  unsigned* dst = (unsigned*)(HTt + (size_t)(blockIdx.x) * Nf * 32 + (size_t)col0 * 32);
  const unsigned* zsrc = (const unsigned*)zone;
  int total = nf * 256;                            // dwords (nf*16 f-rows x 32 shorts each)
  for (int idx = threadIdx.x; idx < total; idx += 128) {
    int f = idx >> 4, jp = idx & 15;
    dst[idx] = zsrc[f * 18 + jp];
  }
}

// ---- src/tgt + Ev/Gv: per-row dots of H with a[:f], a[f:]; exp with constant TM ----
__global__ void gemv_srctgt(const float* __restrict__ H, const float* __restrict__ a,
                            float* __restrict__ src, float* __restrict__ Ev,
                            float* __restrict__ Gv, int f) {
  int row = blockIdx.x * 4 + (threadIdx.x >> 6);
  int lane = threadIdx.x & 63;
  float s = 0.f, t = 0.f;
  for (int k = lane; k < f; k += 64) {
    float h = H[(size_t)row * f + k];
    s += h * a[k];
    t += h * a[f + k];
  }
#pragma unroll
  for (int off = 32; off; off >>= 1) { s += __shfl_down(s, off); t += __shfl_down(t, off); }
  if (lane == 0) {
    src[row] = s;
    Ev[row] = __expf(t - TMC);
    Gv[row] = __expf(0.2f * (t - TMC));
  }
}

// ---- pass1b: masked denom via max(P*Ej,Q*Gj); writes Av,Bv directly; no exp in loop ----
__global__ void pass1b(const unsigned long long* __restrict__ bits, const float* __restrict__ src,
                       const float* __restrict__ Ev, const float* __restrict__ Gv,
                       float* __restrict__ Av, float* __restrict__ Bv) {
  int row = blockIdx.x * 4 + (threadIdx.x >> 6);
  int lane = threadIdx.x & 63;
  float sp = src[row] + TMC;                       // s' = s + TM
  float m = sp > 0.f ? sp : 0.2f * sp;             // lrelu(s') >= lrelu(s+t_j) since t_j <= TM
  float P = __expf(sp - m), Q = __expf(0.2f * sp - m);
  const unsigned long long* brow = bits + (size_t)row * 64;
  float lsum = 0.f;
  for (int k = 0; k < 64; k++) {
    unsigned long long w = brow[k];
    float v = fmaxf(P * Ev[k * 64 + lane], Q * Gv[k * 64 + lane]);  // = exp(lrelu(s+t_j)-m)
    lsum += ((w >> lane) & 1ull) ? v : 0.f;
  }
#pragma unroll
  for (int off = 32; off; off >>= 1) lsum += __shfl_xor(lsum, off);
  if (lane == 0) {
    float inv = 1.0f / lsum;
    Av[row] = P * inv;                             // = exp(s' - c), c = m + ln(lsum)
    Bv[row] = Q * inv;
  }
}

// ---- pass2f: OUT = P @ H, P synthesized on the fly (no exp), bf16 MFMA ----
// block: 4 waves, 32-row i-tile (2 acc tiles/wave), waves split the block's j-range 4 ways.
// B-fragments (HTt, contiguous 1KB/wave) loaded once per j-block, reused over 2 i-tiles.
// Epilogue: LDS combine in FIXED wave order (no atomics), direct coalesced store.
// grid (128, fc, js): z=0 stores to out, z>0 stores to part slab z-1 (reduced afterwards).
template<int NF>
__global__ __launch_bounds__(256) void pass2f(const unsigned* __restrict__ adjW,
                                              const float* __restrict__ Av,
                                              const float* __restrict__ Bv,
                                              const float* __restrict__ Ev,
                                              const float* __restrict__ Gv,
                                              const unsigned short* __restrict__ HTt,
                                              float* __restrict__ out,
                                              float* __restrict__ part, int F, int js) {
  const int W = NF * 16, Wp = W + 4;               // +4 pad: kills quad-aliasing bank conflicts
  __shared__ float zone[32 * Wp];
  int lane = threadIdx.x & 63, wave = threadIdx.x >> 6;
  int quad = lane >> 4, l16 = lane & 15;
  int i0 = blockIdx.x * 32;
  int fc0 = blockIdx.y * W;
  const size_t F32 = (size_t)F * 32;
  int jrange = NROWS / js;
  int jlen = jrange / 4;
  int jstart = blockIdx.z * jrange + wave * jlen;

  float Ai[2], Bi[2];
  const unsigned* arow[2];
#pragma unroll
  for (int ni = 0; ni < 2; ni++) {
    int i = i0 + ni * 16 + l16;
    Ai[ni] = Av[i]; Bi[ni] = Bv[i];
    arow[ni] = adjW + (size_t)i * 128;             // 128 adjacency dwords per row
  }
  v4f acc[2][NF];
#pragma unroll
  for (int ni = 0; ni < 2; ni++)
#pragma unroll
    for (int t = 0; t < NF; t++) acc[ni][t] = (v4f){0.f, 0.f, 0.f, 0.f};

  for (int j0 = jstart; j0 < jstart + jlen; j0 += 32) {
    int jb = j0 + quad * 8;
    float4 e0 = *(const float4*)(Ev + jb), e1 = *(const float4*)(Ev + jb + 4);
    float4 g0 = *(const float4*)(Gv + jb), g1 = *(const float4*)(Gv + jb + 4);
    float ev[8] = {e0.x, e0.y, e0.z, e0.w, e1.x, e1.y, e1.z, e1.w};
    float gv[8] = {g0.x, g0.y, g0.z, g0.w, g1.x, g1.y, g1.z, g1.w};
    // B-fragments: wave reads contiguous 1KB per t; shared across the 2 i-tiles
    const unsigned short* bp = HTt + (size_t)(j0 >> 5) * F32 + (size_t)(fc0 + l16) * 32 + quad * 8;
    v8s bfr[NF];
#pragma unroll
    for (int t = 0; t < NF; t++) bfr[t] = *(const v8s*)(bp + t * 512);
#pragma unroll
    for (int ni = 0; ni < 2; ni++) {
      unsigned bb = arow[ni][j0 >> 5] >> (quad * 8);
      float w[8];
#pragma unroll
      for (int jj = 0; jj < 8; jj++) {
        float v = fmaxf(Ai[ni] * ev[jj], Bi[ni] * gv[jj]);   // exp(lrelu(s+t)-c), factorized
        int msk = ((int)(bb << (31 - jj))) >> 31;            // 0 or -1, no VCC dependency
        w[jj] = __int_as_float(msk & __float_as_int(v));
      }
      union { v8s s; __hip_bfloat162 h[4]; } ua;
#pragma unroll
      for (int p = 0; p < 4; p++)
        ua.h[p] = __float22bfloat162_rn(make_float2(w[2 * p], w[2 * p + 1]));
#pragma unroll
      for (int t = 0; t < NF; t++)
        acc[ni][t] = __builtin_amdgcn_mfma_f32_16x16x32_bf16(ua.s, bfr[t], acc[ni][t], 0, 0, 0);
    }
  }

  // deterministic combine: waves add into zone in fixed order
  for (int w = 0; w < 4; w++) {
    if (wave == w) {
#pragma unroll
      for (int ni = 0; ni < 2; ni++)
#pragma unroll
        for (int t = 0; t < NF; t++)
#pragma unroll
          for (int r = 0; r < 4; r++) {
            int idx = (ni * 16 + quad * 4 + r) * Wp + t * 16 + l16;
            if (w == 0) zone[idx] = acc[ni][t][r];
            else        zone[idx] += acc[ni][t][r];
          }
    }
    __syncthreads();
  }
  float* dst = (blockIdx.z == 0) ? out : part + (size_t)(blockIdx.z - 1) * NROWS * F;
  for (int idx = threadIdx.x; idx < 32 * W; idx += 256) {
    int rrow = idx / W, ccol = idx - rrow * W;
    dst[(size_t)(i0 + rrow) * F + fc0 + ccol] = zone[rrow * Wp + ccol];
  }
}

// ---- deterministic cross-z fold: out[i] += sum of js-1 partial slabs ----
__global__ void reduce_add(const float* __restrict__ part, float* __restrict__ out, int n,
                           int nslab) {
  int i = blockIdx.x * 256 + threadIdx.x;
  if (i < n) {
    float s = out[i];
    for (int z = 0; z < nslab; z++) s += part[(size_t)z * n + i];
    out[i] = s;
  }
}

static void launch_pass2(int NF, dim3 grid, const unsigned* adjW, const float* Av, const float* Bv,
                         const float* Ev, const float* Gv, const unsigned short* HTt, float* out,
                         float* part, int F, int js, hipStream_t stream) {
  switch (NF) {
    case 8: pass2f<8><<<grid, 256, 0, stream>>>(adjW, Av, Bv, Ev, Gv, HTt, out, part, F, js); break;
    case 4: pass2f<4><<<grid, 256, 0, stream>>>(adjW, Av, Bv, Ev, Gv, HTt, out, part, F, js); break;
    default: pass2f<1><<<grid, 256, 0, stream>>>(adjW, Av, Bv, Ev, Gv, HTt, out, part, F, js); break;
  }
}

extern "C" void kernel_launch(void* const* d_in, const int* in_sizes, int n_in,
                              void* d_out, int out_size, void* d_ws, size_t ws_size,
                              hipStream_t stream) {
  static const int fin[8]  = {512, 256, 128, 64, 16, 64, 128, 256};
  static const int fout[8] = {256, 128, 64, 16, 64, 128, 256, 512};

  const float* x = (const float*)d_in[0];
  const int* adj = (const int*)d_in[1];
  char* ws = (char*)d_ws;
  unsigned long long* bits = (unsigned long long*)(ws);                 // 2 MB
  unsigned short* WTall = (unsigned short*)(ws + (2u << 20));           // <1 MB, all layers
  float* H            = (float*)(ws + (6u << 20));                      // 8 MB max
  unsigned short* HTt = (unsigned short*)(ws + (14u << 20));            // 4 MB max
  float* srcv = (float*)(ws + (19u << 20));
  float* Av   = (float*)(ws + (19u << 20) + 49152);
  float* Bv   = (float*)(ws + (19u << 20) + 65536);
  float* Ev   = (float*)(ws + (19u << 20) + 81920);
  float* Gv   = (float*)(ws + (19u << 20) + 98304);
  float* o5   = (float*)(ws + (20u << 20));                             // 1 MB
  float* o6   = (float*)(ws + (21u << 20));                             // 2 MB
  float* o7   = (float*)(ws + (23u << 20));                             // 4 MB
  // partial slabs ((js-1)*N*F*4 <= 6MB) alias H: H's last reader (gemv_srctgt/pass1b) runs
  // before pass2f; next layer's gemm_xw rewrites H afterwards (stream-ordered).
  float* part = H;

  float* outp = (float*)d_out;
  float* xbar = outp;
  float* h1 = outp + (size_t)NROWS * 512;
  float* h2 = h1 + (size_t)NROWS * 256;
  float* h3 = h2 + (size_t)NROWS * 128;
  float* h4 = h3 + (size_t)NROWS * 64;

  float* louts[8] = {h1, h2, h3, h4, o5, o6, o7, xbar};
  const float* lins[8] = {x, h1, h2, h3, h4, o5, o6, o7};

  unsigned short* WT[8];
  { size_t off = 0;
    for (int t = 0; t < 8; t++) { WT[t] = WTall + off; off += (size_t)fin[t] * fout[t]; } }

  pack_adj<<<dim3(4096), dim3(256), 0, stream>>>(adj, bits);

  WTArgs wa;
  for (int t = 0; t < 8; t++) {
    wa.src[t] = (const float*)d_in[2 + 2 * t];
    wa.dst[t] = WT[t];
    wa.K[t] = fin[t];
    wa.F[t] = fout[t];
  }
  transpose_w<<<dim3(16, 16, 8), dim3(32, 8), 0, stream>>>(wa);

  for (int t = 0; t < 8; t++) {
    int K = fin[t], F = fout[t];
    const float* At = (const float*)d_in[3 + 2 * t];
    const float* Xin = lins[t];
    float* Ot = louts[t];

    // Minimize fc (A-build replicas) at NF=8; grid (128, fc, js) = 512 blocks (2/CU).
    // F=512: NF=8 fc=4 js=1 (no slab); 256: fc=2 js=2 (slab 4MB); 128: fc=1 js=4 (6MB);
    // 64: NF=4 fc=1 js=4 (3MB); 16: NF=1 fc=1 js=4 (0.75MB).
    int NF = F >= 128 ? 8 : (F >= 64 ? 4 : 1);
    int fc = F / (16 * NF);
    int js = (F == 512) ? 1 : (F == 256 ? 2 : 4);

    gemm_xw<<<dim3(128, (F + 63) / 64), dim3(128), 0, stream>>>(Xin, WT[t], H, HTt, K, F);
    gemv_srctgt<<<dim3(1024), dim3(256), 0, stream>>>(H, At, srcv, Ev, Gv, F);
    pass1b<<<dim3(1024), dim3(256), 0, stream>>>(bits, srcv, Ev, Gv, Av, Bv);
    launch_pass2(NF, dim3(128, fc, js), (const unsigned*)bits, Av, Bv, Ev, Gv, HTt, Ot, part, F,
                 js, stream);
    if (js > 1)
      reduce_add<<<dim3((NROWS * F + 255) / 256), dim3(256), 0, stream>>>(part, Ot, NROWS * F,
                                                                          js - 1);
  }
}

// Round 13
// 533.348 us; speedup vs baseline: 1.3693x; 1.0778x over previous
//
#include <hip/hip_runtime.h>
#include <hip/hip_bf16.h>
#include <hip/hip_fp16.h>

// GAE: 8 stacked GAT layers on N=4096 nodes, dims 512->256->128->64->16->64->128->256->512.
// Outputs (concat in d_out): x_bar[4096*512], h1[4096*256], h2[4096*128], h3[4096*64], h4[4096*16].
//
// Per layer:
//   H = X @ W                      (bf16 MFMA GEMM, fp32 accum; HTt **fp16** j-tiled layout
//                                   written directly from the GEMM epilogue via LDS)
//   src = H @ a[:f], tgt = H @ a[f:]; Ev=exp(t-TM), Gv=exp(0.2(t-TM)) with CONSTANT TM=12;
//     also Ev16 = half(Ev*2^14), Gv16 = half(Gv*2^4)  (exact pow2 rescale for fp16 A-build)
//   pass1b: lsum_i = sum_{j in N(i)} max(P_i*Ev_j, Q_i*Gv_j); Av=P/lsum, Bv=Q/lsum (fp32)
//   pass2f: OUT[i,:] = sum_j max(Av_i*Ev_j, Bv_i*Gv_j) * H[j,:]  == softmax(lrelu masked) @ H
//     A-fragment built in PACKED fp16 via native vector ops (v_pk_mul_f16 / v_pk_max_f16):
//     Ai' = Av*2^-14, Bi' = Bv*2^-4 so Ai'*Ev16 = Av*Ev <= 1 exactly; masked via 16-bit-field
//     ANDs; fed to mfma_f32_16x16x32_f16.
// pass2f: 4 waves/block, 32-row i-tile, waves split j 4 ways, LDS combine in FIXED wave order,
// j-loop 4x unrolled with dwordx4 adjacency loads. Grid 512 blocks (2/CU) via js splits;
// partial slabs folded by deterministic reduce_add. NO atomics, no memset -> deterministic.

#define NROWS 4096
#define TMC 12.0f

typedef __attribute__((ext_vector_type(8))) short v8s;
typedef __attribute__((ext_vector_type(8))) _Float16 v8h;
typedef __attribute__((ext_vector_type(2))) _Float16 h2v;
typedef __attribute__((ext_vector_type(4))) float v4f;

__device__ inline unsigned short f2bf(float x) {
  union { float f; unsigned u; } v; v.f = x;
  unsigned r = v.u + 0x7fffu + ((v.u >> 16) & 1u);   // RNE
  return (unsigned short)(r >> 16);
}

// ---- pack adj (int32 0/1) -> bitmask, 64 uint64 words per row ----
__global__ void pack_adj(const int* __restrict__ adj, unsigned long long* __restrict__ bits) {
  int row = blockIdx.x;
  int lane = threadIdx.x & 63, wave = threadIdx.x >> 6;
  for (int w = wave; w < 64; w += 4) {
    unsigned long long m = __ballot(adj[(size_t)row * NROWS + w * 64 + lane] > 0);
    if (lane == 0) bits[row * 64 + w] = m;
  }
}

// ---- batched W transpose: fp32 [K][F] -> bf16 [F][K], all 8 layers in one launch ----
struct WTArgs { const float* src[8]; unsigned short* dst[8]; int K[8]; int F[8]; };
__global__ void transpose_w(WTArgs A) {
  int z = blockIdx.z;
  const float* in = A.src[z];
  unsigned short* out = A.dst[z];
  int R = A.K[z], C = A.F[z];
  __shared__ unsigned short tile[32][33];
  int c0 = blockIdx.x * 32, r0 = blockIdx.y * 32;
  if (c0 >= C || r0 >= R) return;          // block-uniform: safe before barrier
#pragma unroll
  for (int dy = 0; dy < 32; dy += 8) {
    int r = r0 + threadIdx.y + dy, c = c0 + threadIdx.x;
    if (r < R && c < C) tile[threadIdx.y + dy][threadIdx.x] = f2bf(in[(size_t)r * C + c]);
  }
  __syncthreads();
#pragma unroll
  for (int dy = 0; dy < 32; dy += 8) {
    int c = c0 + threadIdx.y + dy, r = r0 + threadIdx.x;
    if (r < R && c < C) out[(size_t)c * R + r] = tile[threadIdx.x][threadIdx.y + dy];
  }
}

// ---- C[4096][Nf] = A_f32[4096][K] x B[K][Nf], B given as BT[Nf][K] bf16 ----
// 2 waves/block, 16 rows each; grid (128, ceil(Nf/64)).
// Epilogue writes HTt[j/32][f][j%32] in **fp16** directly (LDS-staged).
__global__ __launch_bounds__(128) void gemm_xw(const float* __restrict__ A,
                                               const unsigned short* __restrict__ BT,
                                               float* __restrict__ C,
                                               unsigned short* __restrict__ HTt,
                                               int K, int Nf) {
  __shared__ unsigned short zone[64 * 36];         // [f_local][j_local], stride 36 vs banks
  int lane = threadIdx.x & 63, wave = threadIdx.x >> 6;
  int quad = lane >> 4, l16 = lane & 15;
  int row0 = blockIdx.x * 32 + wave * 16;
  int col0 = blockIdx.y * 64;
  int nf = Nf - col0; nf = nf > 64 ? 4 : (nf + 15) / 16;
  v4f acc[4] = {{0.f,0.f,0.f,0.f},{0.f,0.f,0.f,0.f},{0.f,0.f,0.f,0.f},{0.f,0.f,0.f,0.f}};
  for (int k0 = 0; k0 < K; k0 += 32) {
    int kk = k0 + quad * 8;
    v8s a = {0,0,0,0,0,0,0,0};
    if (kk < K) {
      float4 f0 = *(const float4*)(A + (size_t)(row0 + l16) * K + kk);
      float4 f1 = *(const float4*)(A + (size_t)(row0 + l16) * K + kk + 4);
      union { v8s s; __hip_bfloat162 h[4]; } ua;
      ua.h[0] = __float22bfloat162_rn(make_float2(f0.x, f0.y));
      ua.h[1] = __float22bfloat162_rn(make_float2(f0.z, f0.w));
      ua.h[2] = __float22bfloat162_rn(make_float2(f1.x, f1.y));
      ua.h[3] = __float22bfloat162_rn(make_float2(f1.z, f1.w));
      a = ua.s;
    }
    for (int t = 0; t < nf; t++) {
      v8s b = {0,0,0,0,0,0,0,0};
      if (kk < K) b = *(const v8s*)(BT + (size_t)(col0 + t * 16 + l16) * K + kk);
      acc[t] = __builtin_amdgcn_mfma_f32_16x16x32_bf16(a, b, acc[t], 0, 0, 0);
    }
  }
  for (int t = 0; t < nf; t++) {
#pragma unroll
    for (int r = 0; r < 4; r++) {
      float v = acc[t][r];
      C[(size_t)(row0 + quad * 4 + r) * Nf + col0 + t * 16 + l16] = v;
      union { _Float16 h; unsigned short s; } cv; cv.h = (_Float16)v;
      zone[(t * 16 + l16) * 36 + wave * 16 + quad * 4 + r] = cv.s;
    }
  }
  __syncthreads();
  // HTt chunk for this block: [row0blk/32][col0..col0+nf*16][0..32): nf*16 f-values x 16 dwords
  unsigned* dst = (unsigned*)(HTt + (size_t)(blockIdx.x) * Nf * 32 + (size_t)col0 * 32);
  const unsigned* zsrc = (const unsigned*)zone;
  int total = nf * 256;                            // dwords (nf*16 f-rows x 32 shorts each)
  for (int idx = threadIdx.x; idx < total; idx += 128) {
    int f = idx >> 4, jp = idx & 15;
    dst[idx] = zsrc[f * 18 + jp];
  }
}

// ---- src/tgt + Ev/Gv (fp32 + scaled fp16): per-row dots of H with a[:f], a[f:] ----
__global__ void gemv_srctgt(const float* __restrict__ H, const float* __restrict__ a,
                            float* __restrict__ src, float* __restrict__ Ev,
                            float* __restrict__ Gv, unsigned short* __restrict__ Ev16,
                            unsigned short* __restrict__ Gv16, int f) {
  int row = blockIdx.x * 4 + (threadIdx.x >> 6);
  int lane = threadIdx.x & 63;
  float s = 0.f, t = 0.f;
  for (int k = lane; k < f; k += 64) {
    float h = H[(size_t)row * f + k];
    s += h * a[k];
    t += h * a[f + k];
  }
#pragma unroll
  for (int off = 32; off; off >>= 1) { s += __shfl_down(s, off); t += __shfl_down(t, off); }
  if (lane == 0) {
    src[row] = s;
    float ev = __expf(t - TMC), gv = __expf(0.2f * (t - TMC));
    Ev[row] = ev; Gv[row] = gv;
    union { _Float16 h; unsigned short u; } ce, cg;
    ce.h = (_Float16)(ev * 16384.f);               // *2^14 (exact pow2)
    cg.h = (_Float16)(gv * 16.f);                  // *2^4  (exact pow2)
    Ev16[row] = ce.u;
    Gv16[row] = cg.u;
  }
}

// ---- pass1b: masked denom via max(P*Ej,Q*Gj); writes Av,Bv directly; fp32 ----
__global__ void pass1b(const unsigned long long* __restrict__ bits, const float* __restrict__ src,
                       const float* __restrict__ Ev, const float* __restrict__ Gv,
                       float* __restrict__ Av, float* __restrict__ Bv) {
  int row = blockIdx.x * 4 + (threadIdx.x >> 6);
  int lane = threadIdx.x & 63;
  float sp = src[row] + TMC;                       // s' = s + TM
  float m = sp > 0.f ? sp : 0.2f * sp;             // lrelu(s') >= lrelu(s+t_j) since t_j <= TM
  float P = __expf(sp - m), Q = __expf(0.2f * sp - m);
  const unsigned long long* brow = bits + (size_t)row * 64;
  float lsum = 0.f;
  for (int k = 0; k < 64; k++) {
    unsigned long long w = brow[k];
    float v = fmaxf(P * Ev[k * 64 + lane], Q * Gv[k * 64 + lane]);  // = exp(lrelu(s+t_j)-m)
    lsum += ((w >> lane) & 1ull) ? v : 0.f;
  }
#pragma unroll
  for (int off = 32; off; off >>= 1) lsum += __shfl_xor(lsum, off);
  if (lane == 0) {
    float inv = 1.0f / lsum;
    Av[row] = P * inv;                             // = exp(s' - c), c = m + ln(lsum)
    Bv[row] = Q * inv;
  }
}

// ---- pass2f: OUT = P @ H, A-fragment in packed fp16 (native vector ops), f16 MFMA ----
// block: 4 waves, 32-row i-tile (2 acc tiles/wave), waves split the block's j-range 4 ways.
// j-loop 4x unrolled (dwordx4 adjacency per 128 j). LDS combine in FIXED wave order.
// grid (128, fc, js): z=0 stores to out, z>0 stores to part slab z-1 (reduced afterwards).
template<int NF>
__global__ __launch_bounds__(256) void pass2f(const unsigned* __restrict__ adjW,
                                              const float* __restrict__ Av,
                                              const float* __restrict__ Bv,
                                              const unsigned short* __restrict__ Ev16,
                                              const unsigned short* __restrict__ Gv16,
                                              const unsigned short* __restrict__ HTt,
                                              float* __restrict__ out,
                                              float* __restrict__ part, int F, int js) {
  const int W = NF * 16, Wp = W + 4;               // +4 pad: kills quad-aliasing bank conflicts
  __shared__ float zone[32 * Wp];
  int lane = threadIdx.x & 63, wave = threadIdx.x >> 6;
  int quad = lane >> 4, l16 = lane & 15;
  int i0 = blockIdx.x * 32;
  int fc0 = blockIdx.y * W;
  const size_t F32 = (size_t)F * 32;
  int jrange = NROWS / js;
  int jlen = jrange / 4;                           // multiple of 128 for js in {1,2,4}
  int jstart = blockIdx.z * jrange + wave * jlen;

  h2v Ai2[2], Bi2[2];
  const unsigned* arow[2];
#pragma unroll
  for (int ni = 0; ni < 2; ni++) {
    int i = i0 + ni * 16 + l16;
    _Float16 ai = (_Float16)(Av[i] * 0x1p-14f);    // Ai'*Ev16 = Av*Ev exactly
    _Float16 bi = (_Float16)(Bv[i] * 0x1p-4f);     // Bi'*Gv16 = Bv*Gv exactly
    Ai2[ni] = (h2v){ai, ai};
    Bi2[ni] = (h2v){bi, bi};
    arow[ni] = adjW + (size_t)i * 128;             // 128 adjacency dwords per row
  }
  v4f acc[2][NF];
#pragma unroll
  for (int ni = 0; ni < 2; ni++)
#pragma unroll
    for (int t = 0; t < NF; t++) acc[ni][t] = (v4f){0.f, 0.f, 0.f, 0.f};

  for (int j0 = jstart; j0 < jstart + jlen; j0 += 128) {
    uint4 aw[2];
    aw[0] = *(const uint4*)(arow[0] + (j0 >> 5));  // 4 iters of adjacency, 16B aligned
    aw[1] = *(const uint4*)(arow[1] + (j0 >> 5));
    unsigned awa[2][4] = {{aw[0].x, aw[0].y, aw[0].z, aw[0].w},
                          {aw[1].x, aw[1].y, aw[1].z, aw[1].w}};
#pragma unroll
    for (int u = 0; u < 4; u++) {
      int ju = j0 + u * 32;
      int jb = ju + quad * 8;
      union { v8s s; h2v h2[4]; } ue, ug;
      ue.s = *(const v8s*)(Ev16 + jb);
      ug.s = *(const v8s*)(Gv16 + jb);
      // B-fragments: wave reads contiguous 1KB per t; shared across the 2 i-tiles
      const unsigned short* bp =
          HTt + (size_t)(ju >> 5) * F32 + (size_t)(fc0 + l16) * 32 + quad * 8;
      union { v8s s; v8h h; } bfr[NF];
#pragma unroll
      for (int t = 0; t < NF; t++) bfr[t].s = *(const v8s*)(bp + t * 512);
#pragma unroll
      for (int ni = 0; ni < 2; ni++) {
        unsigned bb = awa[ni][u] >> (quad * 8);
        union { v8h h; unsigned u32[4]; } ua;
#pragma unroll
        for (int p = 0; p < 4; p++) {
          h2v w2 = __builtin_elementwise_max(Ai2[ni] * ue.h2[p], Bi2[ni] * ug.h2[p]);
          unsigned msk = (((bb >> (2 * p)) & 1u) ? 0x0000FFFFu : 0u)
                       | (((bb >> (2 * p + 1)) & 1u) ? 0xFFFF0000u : 0u);
          union { h2v h2; unsigned u; } tw; tw.h2 = w2;
          ua.u32[p] = tw.u & msk;
        }
#pragma unroll
        for (int t = 0; t < NF; t++)
          acc[ni][t] = __builtin_amdgcn_mfma_f32_16x16x32_f16(ua.h, bfr[t].h, acc[ni][t], 0, 0, 0);
      }
    }
  }

  // deterministic combine: waves add into zone in fixed order
  for (int w = 0; w < 4; w++) {
    if (wave == w) {
#pragma unroll
      for (int ni = 0; ni < 2; ni++)
#pragma unroll
        for (int t = 0; t < NF; t++)
#pragma unroll
          for (int r = 0; r < 4; r++) {
            int idx = (ni * 16 + quad * 4 + r) * Wp + t * 16 + l16;
            if (w == 0) zone[idx] = acc[ni][t][r];
            else        zone[idx] += acc[ni][t][r];
          }
    }
    __syncthreads();
  }
  float* dst = (blockIdx.z == 0) ? out : part + (size_t)(blockIdx.z - 1) * NROWS * F;
  for (int idx = threadIdx.x; idx < 32 * W; idx += 256) {
    int rrow = idx / W, ccol = idx - rrow * W;
    dst[(size_t)(i0 + rrow) * F + fc0 + ccol] = zone[rrow * Wp + ccol];
  }
}

// ---- deterministic cross-z fold: out[i] += sum of js-1 partial slabs ----
__global__ void reduce_add(const float* __restrict__ part, float* __restrict__ out, int n,
                           int nslab) {
  int i = blockIdx.x * 256 + threadIdx.x;
  if (i < n) {
    float s = out[i];
    for (int z = 0; z < nslab; z++) s += part[(size_t)z * n + i];
    out[i] = s;
  }
}

static void launch_pass2(int NF, dim3 grid, const unsigned* adjW, const float* Av, const float* Bv,
                         const unsigned short* Ev16, const unsigned short* Gv16,
                         const unsigned short* HTt, float* out, float* part, int F, int js,
                         hipStream_t stream) {
  switch (NF) {
    case 8: pass2f<8><<<grid, 256, 0, stream>>>(adjW, Av, Bv, Ev16, Gv16, HTt, out, part, F, js);
            break;
    case 4: pass2f<4><<<grid, 256, 0, stream>>>(adjW, Av, Bv, Ev16, Gv16, HTt, out, part, F, js);
            break;
    default: pass2f<1><<<grid, 256, 0, stream>>>(adjW, Av, Bv, Ev16, Gv16, HTt, out, part, F, js);
            break;
  }
}

extern "C" void kernel_launch(void* const* d_in, const int* in_sizes, int n_in,
                              void* d_out, int out_size, void* d_ws, size_t ws_size,
                              hipStream_t stream) {
  static const int fin[8]  = {512, 256, 128, 64, 16, 64, 128, 256};
  static const int fout[8] = {256, 128, 64, 16, 64, 128, 256, 512};

  const float* x = (const float*)d_in[0];
  const int* adj = (const int*)d_in[1];
  char* ws = (char*)d_ws;
  unsigned long long* bits = (unsigned long long*)(ws);                 // 2 MB
  unsigned short* WTall = (unsigned short*)(ws + (2u << 20));           // <1 MB, all layers
  float* H            = (float*)(ws + (6u << 20));                      // 8 MB max
  unsigned short* HTt = (unsigned short*)(ws + (14u << 20));            // 4 MB max (fp16 now)
  float* srcv  = (float*)(ws + (19u << 20));
  float* Av    = (float*)(ws + (19u << 20) + 49152);
  float* Bv    = (float*)(ws + (19u << 20) + 65536);
  float* Ev    = (float*)(ws + (19u << 20) + 81920);
  float* Gv    = (float*)(ws + (19u << 20) + 98304);
  unsigned short* Ev16 = (unsigned short*)(ws + (19u << 20) + 114688);
  unsigned short* Gv16 = (unsigned short*)(ws + (19u << 20) + 122880);
  float* o5    = (float*)(ws + (20u << 20));                            // 1 MB
  float* o6    = (float*)(ws + (21u << 20));                            // 2 MB
  float* o7    = (float*)(ws + (23u << 20));                            // 4 MB
  // partial slabs ((js-1)*N*F*4 <= 6MB) alias H: H's last reader (gemv_srctgt) runs
  // before pass2f; next layer's gemm_xw rewrites H afterwards (stream-ordered).
  float* part = H;

  float* outp = (float*)d_out;
  float* xbar = outp;
  float* h1 = outp + (size_t)NROWS * 512;
  float* h2 = h1 + (size_t)NROWS * 256;
  float* h3 = h2 + (size_t)NROWS * 128;
  float* h4 = h3 + (size_t)NROWS * 64;

  float* louts[8] = {h1, h2, h3, h4, o5, o6, o7, xbar};
  const float* lins[8] = {x, h1, h2, h3, h4, o5, o6, o7};

  unsigned short* WT[8];
  { size_t off = 0;
    for (int t = 0; t < 8; t++) { WT[t] = WTall + off; off += (size_t)fin[t] * fout[t]; } }

  pack_adj<<<dim3(4096), dim3(256), 0, stream>>>(adj, bits);

  WTArgs wa;
  for (int t = 0; t < 8; t++) {
    wa.src[t] = (const float*)d_in[2 + 2 * t];
    wa.dst[t] = WT[t];
    wa.K[t] = fin[t];
    wa.F[t] = fout[t];
  }
  transpose_w<<<dim3(16, 16, 8), dim3(32, 8), 0, stream>>>(wa);

  for (int t = 0; t < 8; t++) {
    int K = fin[t], F = fout[t];
    const float* At = (const float*)d_in[3 + 2 * t];
    const float* Xin = lins[t];
    float* Ot = louts[t];

    // Minimize fc (A-build replicas) at NF=8; grid (128, fc, js) = 512 blocks (2/CU).
    int NF = F >= 128 ? 8 : (F >= 64 ? 4 : 1);
    int fc = F / (16 * NF);
    int js = (F == 512) ? 1 : (F == 256 ? 2 : 4);

    gemm_xw<<<dim3(128, (F + 63) / 64), dim3(128), 0, stream>>>(Xin, WT[t], H, HTt, K, F);
    gemv_srctgt<<<dim3(1024), dim3(256), 0, stream>>>(H, At, srcv, Ev, Gv, Ev16, Gv16, F);
    pass1b<<<dim3(1024), dim3(256), 0, stream>>>(bits, srcv, Ev, Gv, Av, Bv);
    launch_pass2(NF, dim3(128, fc, js), (const unsigned*)bits, Av, Bv, Ev16, Gv16, HTt, Ot, part,
                 F, js, stream);
    if (js > 1)
      reduce_add<<<dim3((NROWS * F + 255) / 256), dim3(256), 0, stream>>>(part, Ot, NROWS * F,
                                                                          js - 1);
  }
}

// Round 14
// 460.341 us; speedup vs baseline: 1.5865x; 1.1586x over previous
//
#include <hip/hip_runtime.h>
#include <hip/hip_bf16.h>
#include <hip/hip_fp16.h>

// GAE: 8 stacked GAT layers on N=4096 nodes, dims 512->256->128->64->16->64->128->256->512.
// Outputs (concat in d_out): x_bar[4096*512], h1[4096*256], h2[4096*128], h3[4096*64], h4[4096*16].
//
// Per layer:
//   H = X @ W                      (bf16 MFMA GEMM, fp32 accum; HTt fp16 j-tiled layout written
//                                   directly from the GEMM epilogue via LDS)
//   src = H @ a[:f], tgt = H @ a[f:]; Ev16 = half(exp(t-TM)*2^14), Gv16 = half(exp(.2(t-TM))*2^4)
//     with CONSTANT TM=12 (factorization exact for any upper bound TM >= max tgt)
//   pass2f: OUT[i,:] = softmax_j(lrelu(s_i+t_j) masked) @ H computed UNNORMALIZED + ones-column:
//     w~_ij = max(P_i*Ev_j, Q_i*Gv_j) in packed fp16 (P,Q from src_i in-kernel — NO pass1 kernel);
//     lsum_i = sum_j w~_ij accumulated by an extra MFMA with B = all-ones (exact row-sums of the
//     same fp16 weights fed to the product MFMAs). js==1: divide in epilogue; js>1: lsum partials
//     (ls0/part_ls) folded + divided in reduce_add.
// pass2f: 4 waves/block, 32-row i-tile, waves split j 4 ways, LDS combine in FIXED wave order
// (lsum rides in the pad column), j-loop 4x unrolled with dwordx4 adjacency loads. Grid 512
// blocks (2/CU) via js splits. NO atomics, no memset -> bitwise deterministic.

#define NROWS 4096
#define TMC 12.0f

typedef __attribute__((ext_vector_type(8))) short v8s;
typedef __attribute__((ext_vector_type(8))) _Float16 v8h;
typedef __attribute__((ext_vector_type(2))) _Float16 h2v;
typedef __attribute__((ext_vector_type(4))) float v4f;

__device__ inline unsigned short f2bf(float x) {
  union { float f; unsigned u; } v; v.f = x;
  unsigned r = v.u + 0x7fffu + ((v.u >> 16) & 1u);   // RNE
  return (unsigned short)(r >> 16);
}

// ---- pack adj (int32 0/1) -> bitmask, 64 uint64 words per row ----
__global__ void pack_adj(const int* __restrict__ adj, unsigned long long* __restrict__ bits) {
  int row = blockIdx.x;
  int lane = threadIdx.x & 63, wave = threadIdx.x >> 6;
  for (int w = wave; w < 64; w += 4) {
    unsigned long long m = __ballot(adj[(size_t)row * NROWS + w * 64 + lane] > 0);
    if (lane == 0) bits[row * 64 + w] = m;
  }
}

// ---- batched W transpose: fp32 [K][F] -> bf16 [F][K], all 8 layers in one launch ----
struct WTArgs { const float* src[8]; unsigned short* dst[8]; int K[8]; int F[8]; };
__global__ void transpose_w(WTArgs A) {
  int z = blockIdx.z;
  const float* in = A.src[z];
  unsigned short* out = A.dst[z];
  int R = A.K[z], C = A.F[z];
  __shared__ unsigned short tile[32][33];
  int c0 = blockIdx.x * 32, r0 = blockIdx.y * 32;
  if (c0 >= C || r0 >= R) return;          // block-uniform: safe before barrier
#pragma unroll
  for (int dy = 0; dy < 32; dy += 8) {
    int r = r0 + threadIdx.y + dy, c = c0 + threadIdx.x;
    if (r < R && c < C) tile[threadIdx.y + dy][threadIdx.x] = f2bf(in[(size_t)r * C + c]);
  }
  __syncthreads();
#pragma unroll
  for (int dy = 0; dy < 32; dy += 8) {
    int c = c0 + threadIdx.y + dy, r = r0 + threadIdx.x;
    if (r < R && c < C) out[(size_t)c * R + r] = tile[threadIdx.x][threadIdx.y + dy];
  }
}

// ---- C[4096][Nf] = A_f32[4096][K] x B[K][Nf], B given as BT[Nf][K] bf16 ----
// 2 waves/block, 16 rows each; grid (128, ceil(Nf/64)).
// Epilogue writes HTt[j/32][f][j%32] in fp16 directly (LDS-staged).
__global__ __launch_bounds__(128) void gemm_xw(const float* __restrict__ A,
                                               const unsigned short* __restrict__ BT,
                                               float* __restrict__ C,
                                               unsigned short* __restrict__ HTt,
                                               int K, int Nf) {
  __shared__ unsigned short zone[64 * 36];         // [f_local][j_local], stride 36 vs banks
  int lane = threadIdx.x & 63, wave = threadIdx.x >> 6;
  int quad = lane >> 4, l16 = lane & 15;
  int row0 = blockIdx.x * 32 + wave * 16;
  int col0 = blockIdx.y * 64;
  int nf = Nf - col0; nf = nf > 64 ? 4 : (nf + 15) / 16;
  v4f acc[4] = {{0.f,0.f,0.f,0.f},{0.f,0.f,0.f,0.f},{0.f,0.f,0.f,0.f},{0.f,0.f,0.f,0.f}};
  for (int k0 = 0; k0 < K; k0 += 32) {
    int kk = k0 + quad * 8;
    v8s a = {0,0,0,0,0,0,0,0};
    if (kk < K) {
      float4 f0 = *(const float4*)(A + (size_t)(row0 + l16) * K + kk);
      float4 f1 = *(const float4*)(A + (size_t)(row0 + l16) * K + kk + 4);
      union { v8s s; __hip_bfloat162 h[4]; } ua;
      ua.h[0] = __float22bfloat162_rn(make_float2(f0.x, f0.y));
      ua.h[1] = __float22bfloat162_rn(make_float2(f0.z, f0.w));
      ua.h[2] = __float22bfloat162_rn(make_float2(f1.x, f1.y));
      ua.h[3] = __float22bfloat162_rn(make_float2(f1.z, f1.w));
      a = ua.s;
    }
    for (int t = 0; t < nf; t++) {
      v8s b = {0,0,0,0,0,0,0,0};
      if (kk < K) b = *(const v8s*)(BT + (size_t)(col0 + t * 16 + l16) * K + kk);
      acc[t] = __builtin_amdgcn_mfma_f32_16x16x32_bf16(a, b, acc[t], 0, 0, 0);
    }
  }
  for (int t = 0; t < nf; t++) {
#pragma unroll
    for (int r = 0; r < 4; r++) {
      float v = acc[t][r];
      C[(size_t)(row0 + quad * 4 + r) * Nf + col0 + t * 16 + l16] = v;
      union { _Float16 h; unsigned short s; } cv; cv.h = (_Float16)v;
      zone[(t * 16 + l16) * 36 + wave * 16 + quad * 4 + r] = cv.s;
    }
  }
  __syncthreads();
  unsigned* dst = (unsigned*)(HTt + (size_t)(blockIdx.x) * Nf * 32 + (size_t)col0 * 32);
  const unsigned* zsrc = (const unsigned*)zone;
  int total = nf * 256;                            // dwords (nf*16 f-rows x 32 shorts each)
  for (int idx = threadIdx.x; idx < total; idx += 128) {
    int f = idx >> 4, jp = idx & 15;
    dst[idx] = zsrc[f * 18 + jp];
  }
}

// ---- src + scaled-fp16 Ev/Gv: per-row dots of H with a[:f], a[f:] ----
__global__ void gemv_srctgt(const float* __restrict__ H, const float* __restrict__ a,
                            float* __restrict__ src, unsigned short* __restrict__ Ev16,
                            unsigned short* __restrict__ Gv16, int f) {
  int row = blockIdx.x * 4 + (threadIdx.x >> 6);
  int lane = threadIdx.x & 63;
  float s = 0.f, t = 0.f;
  for (int k = lane; k < f; k += 64) {
    float h = H[(size_t)row * f + k];
    s += h * a[k];
    t += h * a[f + k];
  }
#pragma unroll
  for (int off = 32; off; off >>= 1) { s += __shfl_down(s, off); t += __shfl_down(t, off); }
  if (lane == 0) {
    src[row] = s;
    union { _Float16 h; unsigned short u; } ce, cg;
    ce.h = (_Float16)(__expf(t - TMC) * 16384.f);  // *2^14 (exact pow2)
    cg.h = (_Float16)(__expf(0.2f * (t - TMC)) * 16.f);   // *2^4 (exact pow2)
    Ev16[row] = ce.u;
    Gv16[row] = cg.u;
  }
}

// ---- pass2f: OUT = P @ H unnormalized + MFMA ones-column lsum; packed fp16 A-build ----
// grid (128, fc, js): z=0 stores to out (+ls0), z>0 to part slab z-1 (+part_ls).
template<int NF>
__global__ __launch_bounds__(256) void pass2f(const unsigned* __restrict__ adjW,
                                              const float* __restrict__ src,
                                              const unsigned short* __restrict__ Ev16,
                                              const unsigned short* __restrict__ Gv16,
                                              const unsigned short* __restrict__ HTt,
                                              float* __restrict__ out,
                                              float* __restrict__ part,
                                              float* __restrict__ ls0,
                                              float* __restrict__ part_ls, int F, int js) {
  const int W = NF * 16, Wp = W + 4;               // pad col W holds lsum; rest kills conflicts
  __shared__ float zone[32 * Wp];
  int lane = threadIdx.x & 63, wave = threadIdx.x >> 6;
  int quad = lane >> 4, l16 = lane & 15;
  int i0 = blockIdx.x * 32;
  int fc0 = blockIdx.y * W;
  const size_t F32 = (size_t)F * 32;
  int jrange = NROWS / js;
  int jlen = jrange / 4;                           // multiple of 128 for js in {1,2,4}
  int jstart = blockIdx.z * jrange + wave * jlen;

  h2v Ai2[2], Bi2[2];
  const unsigned* arow[2];
#pragma unroll
  for (int ni = 0; ni < 2; ni++) {
    int i = i0 + ni * 16 + l16;
    float sp = src[i] + TMC;                       // s' = s + TM
    float m = sp > 0.f ? sp : 0.2f * sp;           // lrelu(s') >= lrelu(s+t_j) since t_j <= TM
    _Float16 ai = (_Float16)(__expf(sp - m) * 0x1p-14f);       // Ai'*Ev16 = exp(e-m) exactly
    _Float16 bi = (_Float16)(__expf(0.2f * sp - m) * 0x1p-4f); // Bi'*Gv16 = exp(.2e-m) exactly
    Ai2[ni] = (h2v){ai, ai};
    Bi2[ni] = (h2v){bi, bi};
    arow[ni] = adjW + (size_t)i * 128;             // 128 adjacency dwords per row
  }
  const v8h ones = {(_Float16)1.f, (_Float16)1.f, (_Float16)1.f, (_Float16)1.f,
                    (_Float16)1.f, (_Float16)1.f, (_Float16)1.f, (_Float16)1.f};
  v4f acc[2][NF], accl[2];
#pragma unroll
  for (int ni = 0; ni < 2; ni++) {
    accl[ni] = (v4f){0.f, 0.f, 0.f, 0.f};
#pragma unroll
    for (int t = 0; t < NF; t++) acc[ni][t] = (v4f){0.f, 0.f, 0.f, 0.f};
  }

  for (int j0 = jstart; j0 < jstart + jlen; j0 += 128) {
    uint4 aw[2];
    aw[0] = *(const uint4*)(arow[0] + (j0 >> 5));  // 4 iters of adjacency, 16B aligned
    aw[1] = *(const uint4*)(arow[1] + (j0 >> 5));
    unsigned awa[2][4] = {{aw[0].x, aw[0].y, aw[0].z, aw[0].w},
                          {aw[1].x, aw[1].y, aw[1].z, aw[1].w}};
#pragma unroll
    for (int u = 0; u < 4; u++) {
      int ju = j0 + u * 32;
      int jb = ju + quad * 8;
      union { v8s s; h2v h2[4]; } ue, ug;
      ue.s = *(const v8s*)(Ev16 + jb);
      ug.s = *(const v8s*)(Gv16 + jb);
      const unsigned short* bp =
          HTt + (size_t)(ju >> 5) * F32 + (size_t)(fc0 + l16) * 32 + quad * 8;
      union { v8s s; v8h h; } bfr[NF];
#pragma unroll
      for (int t = 0; t < NF; t++) bfr[t].s = *(const v8s*)(bp + t * 512);
#pragma unroll
      for (int ni = 0; ni < 2; ni++) {
        unsigned bb = awa[ni][u] >> (quad * 8);
        union { v8h h; unsigned u32[4]; } ua;
#pragma unroll
        for (int p = 0; p < 4; p++) {
          h2v w2 = __builtin_elementwise_max(Ai2[ni] * ue.h2[p], Bi2[ni] * ug.h2[p]);
          unsigned msk = (((bb >> (2 * p)) & 1u) ? 0x0000FFFFu : 0u)
                       | (((bb >> (2 * p + 1)) & 1u) ? 0xFFFF0000u : 0u);
          union { h2v h2; unsigned u; } tw; tw.h2 = w2;
          ua.u32[p] = tw.u & msk;
        }
#pragma unroll
        for (int t = 0; t < NF; t++)
          acc[ni][t] = __builtin_amdgcn_mfma_f32_16x16x32_f16(ua.h, bfr[t].h, acc[ni][t], 0, 0, 0);
        accl[ni] = __builtin_amdgcn_mfma_f32_16x16x32_f16(ua.h, ones, accl[ni], 0, 0, 0);
      }
    }
  }

  // deterministic combine: waves add into zone in fixed order (lsum in column W)
  for (int w = 0; w < 4; w++) {
    if (wave == w) {
#pragma unroll
      for (int ni = 0; ni < 2; ni++) {
#pragma unroll
        for (int t = 0; t < NF; t++)
#pragma unroll
          for (int r = 0; r < 4; r++) {
            int idx = (ni * 16 + quad * 4 + r) * Wp + t * 16 + l16;
            if (w == 0) zone[idx] = acc[ni][t][r];
            else        zone[idx] += acc[ni][t][r];
          }
        if (l16 == 0) {
#pragma unroll
          for (int r = 0; r < 4; r++) {
            int idx = (ni * 16 + quad * 4 + r) * Wp + W;
            if (w == 0) zone[idx] = accl[ni][r];
            else        zone[idx] += accl[ni][r];
          }
        }
      }
    }
    __syncthreads();
  }

  if (js == 1) {
    if (threadIdx.x < 32) zone[threadIdx.x * Wp + W] = 1.0f / zone[threadIdx.x * Wp + W];
    __syncthreads();
    for (int idx = threadIdx.x; idx < 32 * W; idx += 256) {
      int rrow = idx / W, ccol = idx - rrow * W;
      out[(size_t)(i0 + rrow) * F + fc0 + ccol] = zone[rrow * Wp + ccol] * zone[rrow * Wp + W];
    }
  } else {
    float* dst = (blockIdx.z == 0) ? out : part + (size_t)(blockIdx.z - 1) * NROWS * F;
    for (int idx = threadIdx.x; idx < 32 * W; idx += 256) {
      int rrow = idx / W, ccol = idx - rrow * W;
      dst[(size_t)(i0 + rrow) * F + fc0 + ccol] = zone[rrow * Wp + ccol];
    }
    if (threadIdx.x < 32) {
      float l = zone[threadIdx.x * Wp + W];
      if (blockIdx.z == 0) ls0[i0 + threadIdx.x] = l;             // fc dups write same value
      else part_ls[(size_t)(blockIdx.z - 1) * NROWS + i0 + threadIdx.x] = l;
    }
  }
}

// ---- deterministic cross-z fold + normalize: out = (out + sum slabs) / (ls0 + sum part_ls) ----
__global__ void reduce_add(const float* __restrict__ part, const float* __restrict__ part_ls,
                           const float* __restrict__ ls0, float* __restrict__ out, int n, int F,
                           int nslab) {
  int i = blockIdx.x * 256 + threadIdx.x;
  if (i < n) {
    int row = i / F;                               // F is a power of two
    float s = out[i];
    float l = ls0[row];
    for (int z = 0; z < nslab; z++) s += part[(size_t)z * n + i];
    for (int z = 0; z < nslab; z++) l += part_ls[(size_t)z * NROWS + row];
    out[i] = s / l;
  }
}

static void launch_pass2(int NF, dim3 grid, const unsigned* adjW, const float* src,
                         const unsigned short* Ev16, const unsigned short* Gv16,
                         const unsigned short* HTt, float* out, float* part, float* ls0,
                         float* part_ls, int F, int js, hipStream_t stream) {
  switch (NF) {
    case 8: pass2f<8><<<grid, 256, 0, stream>>>(adjW, src, Ev16, Gv16, HTt, out, part, ls0,
                                                part_ls, F, js); break;
    case 4: pass2f<4><<<grid, 256, 0, stream>>>(adjW, src, Ev16, Gv16, HTt, out, part, ls0,
                                                part_ls, F, js); break;
    default: pass2f<1><<<grid, 256, 0, stream>>>(adjW, src, Ev16, Gv16, HTt, out, part, ls0,
                                                 part_ls, F, js); break;
  }
}

extern "C" void kernel_launch(void* const* d_in, const int* in_sizes, int n_in,
                              void* d_out, int out_size, void* d_ws, size_t ws_size,
                              hipStream_t stream) {
  static const int fin[8]  = {512, 256, 128, 64, 16, 64, 128, 256};
  static const int fout[8] = {256, 128, 64, 16, 64, 128, 256, 512};

  const float* x = (const float*)d_in[0];
  const int* adj = (const int*)d_in[1];
  char* ws = (char*)d_ws;
  unsigned long long* bits = (unsigned long long*)(ws);                 // 2 MB
  unsigned short* WTall = (unsigned short*)(ws + (2u << 20));           // <1 MB, all layers
  float* H            = (float*)(ws + (6u << 20));                      // 8 MB max
  unsigned short* HTt = (unsigned short*)(ws + (14u << 20));            // 4 MB max (fp16)
  float* srcv    = (float*)(ws + (19u << 20));                          // 16 KB
  float* ls0     = (float*)(ws + (19u << 20) + 49152);                  // 16 KB
  float* part_ls = (float*)(ws + (19u << 20) + 65536);                  // 48 KB (3 slabs)
  unsigned short* Ev16 = (unsigned short*)(ws + (19u << 20) + 114688);  // 8 KB
  unsigned short* Gv16 = (unsigned short*)(ws + (19u << 20) + 122880);  // 8 KB
  float* o5    = (float*)(ws + (20u << 20));                            // 1 MB
  float* o6    = (float*)(ws + (21u << 20));                            // 2 MB
  float* o7    = (float*)(ws + (23u << 20));                            // 4 MB
  // partial slabs ((js-1)*N*F*4 <= 6MB) alias H: H's last reader (gemv_srctgt) runs
  // before pass2f; next layer's gemm_xw rewrites H afterwards (stream-ordered).
  float* part = H;

  float* outp = (float*)d_out;
  float* xbar = outp;
  float* h1 = outp + (size_t)NROWS * 512;
  float* h2 = h1 + (size_t)NROWS * 256;
  float* h3 = h2 + (size_t)NROWS * 128;
  float* h4 = h3 + (size_t)NROWS * 64;

  float* louts[8] = {h1, h2, h3, h4, o5, o6, o7, xbar};
  const float* lins[8] = {x, h1, h2, h3, h4, o5, o6, o7};

  unsigned short* WT[8];
  { size_t off = 0;
    for (int t = 0; t < 8; t++) { WT[t] = WTall + off; off += (size_t)fin[t] * fout[t]; } }

  pack_adj<<<dim3(4096), dim3(256), 0, stream>>>(adj, bits);

  WTArgs wa;
  for (int t = 0; t < 8; t++) {
    wa.src[t] = (const float*)d_in[2 + 2 * t];
    wa.dst[t] = WT[t];
    wa.K[t] = fin[t];
    wa.F[t] = fout[t];
  }
  transpose_w<<<dim3(16, 16, 8), dim3(32, 8), 0, stream>>>(wa);

  for (int t = 0; t < 8; t++) {
    int K = fin[t], F = fout[t];
    const float* At = (const float*)d_in[3 + 2 * t];
    const float* Xin = lins[t];
    float* Ot = louts[t];

    // Minimize fc (A-build replicas) at NF=8; grid (128, fc, js) = 512 blocks (2/CU).
    int NF = F >= 128 ? 8 : (F >= 64 ? 4 : 1);
    int fc = F / (16 * NF);
    int js = (F == 512) ? 1 : (F == 256 ? 2 : 4);

    gemm_xw<<<dim3(128, (F + 63) / 64), dim3(128), 0, stream>>>(Xin, WT[t], H, HTt, K, F);
    gemv_srctgt<<<dim3(1024), dim3(256), 0, stream>>>(H, At, srcv, Ev16, Gv16, F);
    launch_pass2(NF, dim3(128, fc, js), (const unsigned*)bits, srcv, Ev16, Gv16, HTt, Ot, part,
                 ls0, part_ls, F, js, stream);
    if (js > 1)
      reduce_add<<<dim3((NROWS * F + 255) / 256), dim3(256), 0, stream>>>(part, part_ls, ls0, Ot,
                                                                          NROWS * F, F, js - 1);
  }
}